// Round 4
// baseline (1347.398 us; speedup 1.0000x reference)
//
#include <hip/hip_runtime.h>

// NodeModel: edge MLP (Lin->BN->ReLU->Lin) -> scatter_add -> node MLP (same).
// R4: barrier-free wave-autonomous edge kernels (A-frags gathered directly
// from global, LDS only for weights), 2-deep software pipeline, counting-sort
// by dest + run-combined fp32 atomics, x pre-converted to f16.

typedef _Float16 half8  __attribute__((ext_vector_type(8)));
typedef _Float16 half4h __attribute__((ext_vector_type(4)));
typedef float    floatx4 __attribute__((ext_vector_type(4)));

#define MFMA16(a, b, c) __builtin_amdgcn_mfma_f32_16x16x32_f16(a, b, c, 0, 0, 0)

__device__ __forceinline__ float col_reduce16(float v) {
    v += __shfl_xor(v, 16, 64);
    v += __shfl_xor(v, 32, 64);
    return v;
}

// ---------------------------------------------------------------- k_prep ----
__global__ void k_prep(const float* __restrict__ w1a, const float* __restrict__ w2a,
                       const float* __restrict__ w1b, const float* __restrict__ w2b,
                       _Float16* __restrict__ w1at, _Float16* __restrict__ w2at,
                       _Float16* __restrict__ w1bt, _Float16* __restrict__ w2bt) {
    int i = blockIdx.x * 256 + threadIdx.x;           // 65536 total
    if (i < 16384) {
        int n = i >> 7, k = i & 127;
        w1at[n * 128 + k] = (_Float16)w1a[k * 128 + n];
    } else if (i < 32768) {
        int j = i - 16384; int n = j >> 7, k = j & 127;
        w2at[n * 128 + k] = (_Float16)w2a[k * 128 + n];
    } else if (i < 57344) {
        int j = i - 32768; int n = j / 192, k = j - n * 192;
        w1bt[n * 192 + k] = (_Float16)w1b[k * 128 + n];
    } else if (i < 65536) {
        int j = i - 57344; int n = j >> 7, k = j & 127;
        w2bt[n * 128 + k] = (_Float16)w2b[k * 64 + n];
    }
}

// --------------------------------------------------------------- k_cvt_x ----
__global__ void k_cvt_x(const float* __restrict__ x, _Float16* __restrict__ x16, int n4) {
    int i = blockIdx.x * 512 + threadIdx.x;
    if (i < n4) {
        floatx4 v = ((const floatx4*)x)[i];
        half4h h = {(_Float16)v[0], (_Float16)v[1], (_Float16)v[2], (_Float16)v[3]};
        ((half4h*)x16)[i] = h;
    }
}

// ----------------------------------------------------------- sort kernels ---
__global__ void k_hist(const int* __restrict__ coli, int* __restrict__ cnt, int E) {
    int i = blockIdx.x * 256 + threadIdx.x;
    if (i < E) atomicAdd(&cnt[coli[i]], 1);
}

__global__ void k_scan(const int* __restrict__ cnt, int* __restrict__ cursor, int N) {
    __shared__ int sP[1024];
    int tid = threadIdx.x;
    int chunk = (N + 1023) >> 10;
    int base = tid * chunk;
    int s = 0;
    for (int i = 0; i < chunk; i++) { int idx = base + i; if (idx < N) s += cnt[idx]; }
    sP[tid] = s; __syncthreads();
    for (int off = 1; off < 1024; off <<= 1) {
        int v = (tid >= off) ? sP[tid - off] : 0;
        __syncthreads();
        sP[tid] += v;
        __syncthreads();
    }
    int excl = sP[tid] - s;
    for (int i = 0; i < chunk; i++) {
        int idx = base + i;
        if (idx < N) { cursor[idx] = excl; excl += cnt[idx]; }
    }
}

__global__ void k_perm(const int* __restrict__ coli, const int* __restrict__ rowi,
                       int* __restrict__ cursor, int* __restrict__ perm,
                       int* __restrict__ srow, int* __restrict__ sdst, int E) {
    int e = blockIdx.x * 256 + threadIdx.x;
    if (e < E) {
        int c = coli[e];
        int pos = atomicAdd(&cursor[c], 1);
        perm[pos] = e;
        srow[pos] = rowi[e];
        sdst[pos] = c;
    }
}

// ---------------------------------------------------------- k_edge_stats ----
// Barrier-free: each wave owns 16 edges/iter (original order). A-frags loaded
// directly from global (x16 gather b128, ea f32->f16 cvt). 2-deep pipeline.
__global__ __launch_bounds__(512, 4) void k_edge_stats(
    const _Float16* __restrict__ x16, const int* __restrict__ rowi,
    const float* __restrict__ ea, const _Float16* __restrict__ w1t,
    float* __restrict__ gsum, float* __restrict__ gsq, int nCh) {
    __shared__ _Float16 sW[128][136];
    __shared__ float sSum[128], sSq[128];
    const int tid = threadIdx.x, lane = tid & 63, wv = tid >> 6;
    const int lm = lane & 15, q = lane >> 4, koff = q * 8;
    {
        int n = tid >> 2, seg = (tid & 3) * 32;
        const half8* s = (const half8*)(w1t + n * 128 + seg);
        half8* d = (half8*)&sW[n][seg];
        d[0] = s[0]; d[1] = s[1]; d[2] = s[2]; d[3] = s[3];
    }
    if (tid < 128) { sSum[tid] = 0.f; sSq[tid] = 0.f; }
    __syncthreads();

    float sAcc[8], ssAcc[8];
#pragma unroll
    for (int i = 0; i < 8; i++) { sAcc[i] = 0.f; ssAcc[i] = 0.f; }

    const int stride = gridDim.x * 8;
    const int gw = blockIdx.x * 8 + wv;
    int r1 = 0;
    half8 xf1[2]; floatx4 ef1[4];
    if (gw < nCh) {
        long p0 = (long)gw * 16 + lm;
        int r0 = rowi[p0];
        xf1[0] = *(const half8*)(x16 + (long)r0 * 64 + koff);
        xf1[1] = *(const half8*)(x16 + (long)r0 * 64 + 32 + koff);
        const floatx4* e0 = (const floatx4*)(ea + p0 * 64);
        ef1[0] = e0[q * 2]; ef1[1] = e0[q * 2 + 1];
        ef1[2] = e0[8 + q * 2]; ef1[3] = e0[8 + q * 2 + 1];
        int c1 = min(gw + stride, nCh - 1);
        r1 = rowi[(long)c1 * 16 + lm];
    }
    for (int t = gw; t < nCh; t += stride) {
        int c2 = min(t + 2 * stride, nCh - 1);
        int r2 = rowi[(long)c2 * 16 + lm];
        int c1v = min(t + stride, nCh - 1);
        half8 xf2[2]; floatx4 ef2[4];
        xf2[0] = *(const half8*)(x16 + (long)r1 * 64 + koff);
        xf2[1] = *(const half8*)(x16 + (long)r1 * 64 + 32 + koff);
        {
            const floatx4* e1 = (const floatx4*)(ea + ((long)c1v * 16 + lm) * 64);
            ef2[0] = e1[q * 2]; ef2[1] = e1[q * 2 + 1];
            ef2[2] = e1[8 + q * 2]; ef2[3] = e1[8 + q * 2 + 1];
        }
        half8 a[4];
        a[0] = xf1[0]; a[1] = xf1[1];
#pragma unroll
        for (int j = 0; j < 4; j++) {
            a[2][j] = (_Float16)ef1[0][j]; a[2][j + 4] = (_Float16)ef1[1][j];
            a[3][j] = (_Float16)ef1[2][j]; a[3][j + 4] = (_Float16)ef1[3][j];
        }
#pragma unroll
        for (int nt = 0; nt < 8; nt++) {
            floatx4 acc = {0.f, 0.f, 0.f, 0.f};
            const int c = nt * 16 + lm;
#pragma unroll
            for (int kb = 0; kb < 4; kb++)
                acc = MFMA16(a[kb], *(const half8*)&sW[c][kb * 32 + koff], acc);
            sAcc[nt]  += acc[0] + acc[1] + acc[2] + acc[3];
            ssAcc[nt] += acc[0]*acc[0] + acc[1]*acc[1] + acc[2]*acc[2] + acc[3]*acc[3];
        }
        r1 = r2;
        xf1[0] = xf2[0]; xf1[1] = xf2[1];
        ef1[0] = ef2[0]; ef1[1] = ef2[1]; ef1[2] = ef2[2]; ef1[3] = ef2[3];
    }
#pragma unroll
    for (int nt = 0; nt < 8; nt++) {
        float s  = col_reduce16(sAcc[nt]);
        float ss = col_reduce16(ssAcc[nt]);
        if (q == 0) { atomicAdd(&sSum[nt * 16 + lm], s); atomicAdd(&sSq[nt * 16 + lm], ss); }
    }
    __syncthreads();
    if (tid < 128) {
        int slot = blockIdx.x & 15;
        unsafeAtomicAdd(&gsum[slot * 128 + tid], sSum[tid]);
        unsafeAtomicAdd(&gsq[slot * 128 + tid], sSq[tid]);
    }
}

// ------------------------------------------------------------ k_finalize ----
__global__ void k_finalize(const float* __restrict__ sums, const float* __restrict__ sqs,
                           const float* __restrict__ gamma, const float* __restrict__ beta,
                           float* __restrict__ scale, float* __restrict__ shift, float count) {
    int i = threadIdx.x;   // 128
    float s = 0.f, ssq = 0.f;
    for (int j = 0; j < 16; j++) { s += sums[j * 128 + i]; ssq += sqs[j * 128 + i]; }
    float mu = s / count;
    float var = ssq / count - mu * mu;
    float sc = gamma[i] * rsqrtf(var + 1e-5f);
    scale[i] = sc;
    shift[i] = beta[i] - mu * sc;
}

// ------------------------------------------------------------ k_edge_mlp ----
// Sorted order; barrier-free waves; per-wave LDS transpose buffer; scatter
// with uniform-dest fast path + in-lane run combining; fp32 atomics.
__global__ __launch_bounds__(1024, 4) void k_edge_mlp(
    const _Float16* __restrict__ x16, const float* __restrict__ ea,
    const int* __restrict__ perm, const int* __restrict__ srow, const int* __restrict__ sdst,
    const _Float16* __restrict__ w1t, const _Float16* __restrict__ w2t,
    const float* __restrict__ scale, const float* __restrict__ shift, const float* __restrict__ b2a,
    float* __restrict__ agg, int nCh) {
    __shared__ _Float16 sW1[128][136];
    __shared__ _Float16 sW2[128][136];
    __shared__ _Float16 sT[16][128][20];   // per-wave transpose scratch
    __shared__ float sScale[128], sShift[128], sB2[128];
    const int tid = threadIdx.x, lane = tid & 63, wv = tid >> 6;
    const int lm = lane & 15, q = lane >> 4, koff = q * 8;
    {
        int n = tid >> 3, seg = (tid & 7) * 16;
        const half8* s1 = (const half8*)(w1t + n * 128 + seg);
        half8* d1 = (half8*)&sW1[n][seg];
        d1[0] = s1[0]; d1[1] = s1[1];
        const half8* s2 = (const half8*)(w2t + n * 128 + seg);
        half8* d2 = (half8*)&sW2[n][seg];
        d2[0] = s2[0]; d2[1] = s2[1];
    }
    if (tid < 128) { sScale[tid] = scale[tid]; sShift[tid] = shift[tid]; sB2[tid] = b2a[tid]; }
    __syncthreads();

    const int stride = gridDim.x * 16;
    const int gw = blockIdx.x * 16 + wv;
    int di0 = 0, di1 = 0, ri1 = 0, pi1 = 0;
    half8 xf1[2]; floatx4 ef1[4];
    if (gw < nCh) {
        long p0 = (long)gw * 16 + lm;
        di0 = sdst[p0];
        int r0 = srow[p0], e0i = perm[p0];
        xf1[0] = *(const half8*)(x16 + (long)r0 * 64 + koff);
        xf1[1] = *(const half8*)(x16 + (long)r0 * 64 + 32 + koff);
        const floatx4* e0 = (const floatx4*)(ea + (long)e0i * 64);
        ef1[0] = e0[q * 2]; ef1[1] = e0[q * 2 + 1];
        ef1[2] = e0[8 + q * 2]; ef1[3] = e0[8 + q * 2 + 1];
        long p1 = (long)min(gw + stride, nCh - 1) * 16 + lm;
        di1 = sdst[p1]; ri1 = srow[p1]; pi1 = perm[p1];
    }
    _Float16 (*tT)[20] = sT[wv];
    for (int t = gw; t < nCh; t += stride) {
        long p2 = (long)min(t + 2 * stride, nCh - 1) * 16 + lm;
        int ri2 = srow[p2], pi2 = perm[p2], di2 = sdst[p2];
        half8 xf2[2]; floatx4 ef2[4];
        xf2[0] = *(const half8*)(x16 + (long)ri1 * 64 + koff);
        xf2[1] = *(const half8*)(x16 + (long)ri1 * 64 + 32 + koff);
        {
            const floatx4* e1 = (const floatx4*)(ea + (long)pi1 * 64);
            ef2[0] = e1[q * 2]; ef2[1] = e1[q * 2 + 1];
            ef2[2] = e1[8 + q * 2]; ef2[3] = e1[8 + q * 2 + 1];
        }
        // GEMM1
        half8 a[4];
        a[0] = xf1[0]; a[1] = xf1[1];
#pragma unroll
        for (int j = 0; j < 4; j++) {
            a[2][j] = (_Float16)ef1[0][j]; a[2][j + 4] = (_Float16)ef1[1][j];
            a[3][j] = (_Float16)ef1[2][j]; a[3][j + 4] = (_Float16)ef1[3][j];
        }
        floatx4 acc[8];
#pragma unroll
        for (int nt = 0; nt < 8; nt++) {
            floatx4 v = {0.f, 0.f, 0.f, 0.f};
            const int c = nt * 16 + lm;
#pragma unroll
            for (int kb = 0; kb < 4; kb++)
                v = MFMA16(a[kb], *(const half8*)&sW1[c][kb * 32 + koff], v);
            acc[nt] = v;
        }
        // BN + ReLU -> per-wave transposed LDS (own-wave only: no barrier)
#pragma unroll
        for (int nt = 0; nt < 8; nt++) {
            const int c = nt * 16 + lm;
            float sc = sScale[c], sh = sShift[c];
            half4h h;
#pragma unroll
            for (int r = 0; r < 4; r++)
                h[r] = (_Float16)fmaxf(acc[nt][r] * sc + sh, 0.f);
            *(half4h*)&tT[c][q * 4] = h;
        }
        half8 a2[4];
#pragma unroll
        for (int kb = 0; kb < 4; kb++)
#pragma unroll
            for (int j = 0; j < 8; j++)
                a2[kb][j] = tT[kb * 32 + koff + j][lm];
        // GEMM2
        floatx4 acc2[8];
#pragma unroll
        for (int nt = 0; nt < 8; nt++) {
            floatx4 v = {0.f, 0.f, 0.f, 0.f};
            const int c = nt * 16 + lm;
#pragma unroll
            for (int kb = 0; kb < 4; kb++)
                v = MFMA16(a2[kb], *(const half8*)&sW2[c][kb * 32 + koff], v);
            acc2[nt] = v;
        }
        // scatter (sorted dests): uniform fast path / in-lane run combine
        int d0 = __shfl(di0, q * 4 + 0, 64), d1 = __shfl(di0, q * 4 + 1, 64);
        int d2 = __shfl(di0, q * 4 + 2, 64), d3 = __shfl(di0, q * 4 + 3, 64);
        bool uni = (__shfl(di0, 0, 64) == __shfl(di0, 15, 64));
        if (uni) {
#pragma unroll
            for (int nt = 0; nt < 8; nt++) {
                const int c = nt * 16 + lm;
                float bb = sB2[c];
                float s = acc2[nt][0] + acc2[nt][1] + acc2[nt][2] + acc2[nt][3] + 4.f * bb;
                s = col_reduce16(s);
                if (q == 0) unsafeAtomicAdd(&agg[(size_t)d0 * 128 + c], s);
            }
        } else {
#pragma unroll
            for (int nt = 0; nt < 8; nt++) {
                const int c = nt * 16 + lm;
                float bb = sB2[c];
                float run = acc2[nt][0] + bb;
                if (d1 == d0) run += acc2[nt][1] + bb;
                else { unsafeAtomicAdd(&agg[(size_t)d0 * 128 + c], run); run = acc2[nt][1] + bb; }
                if (d2 == d1) run += acc2[nt][2] + bb;
                else { unsafeAtomicAdd(&agg[(size_t)d1 * 128 + c], run); run = acc2[nt][2] + bb; }
                if (d3 == d2) run += acc2[nt][3] + bb;
                else { unsafeAtomicAdd(&agg[(size_t)d2 * 128 + c], run); run = acc2[nt][3] + bb; }
                unsafeAtomicAdd(&agg[(size_t)d3 * 128 + c], run);
            }
        }
        di0 = di1; di1 = di2; ri1 = ri2; pi1 = pi2;
        xf1[0] = xf2[0]; xf1[1] = xf2[1];
        ef1[0] = ef2[0]; ef1[1] = ef2[1]; ef1[2] = ef2[2]; ef1[3] = ef2[3];
    }
}

// -------------------------------------------------------------- k_node_a ----
__global__ __launch_bounds__(512, 2) void k_node_a(
    const float* __restrict__ x, const float* __restrict__ agg,
    const _Float16* __restrict__ w1bt, float* __restrict__ h3,
    float* __restrict__ gsum, float* __restrict__ gsq, int N) {
    __shared__ _Float16 sIn[128][200];
    __shared__ _Float16 sW[128][200];
    __shared__ float sSum[128], sSq[128];
    const int tid = threadIdx.x, lane = tid & 63, wv = tid >> 6;
    const long e0 = (long)blockIdx.x * 128;

    {
        int n = tid >> 2, seg = (tid & 3) * 48;
        const half8* src = (const half8*)(w1bt + n * 192 + seg);
        half8* dst = (half8*)&sW[n][seg];
        dst[0] = src[0]; dst[1] = src[1]; dst[2] = src[2];
        dst[3] = src[3]; dst[4] = src[4]; dst[5] = src[5];
    }
    if (tid < 128) { sSum[tid] = 0.f; sSq[tid] = 0.f; }
    {
        int m = tid >> 2, seg = tid & 3;
        long gm = e0 + m;
        bool valid = gm < N;
        const float* srcx = x + gm * 64 + seg * 16;
        _Float16* dstx = &sIn[m][seg * 16];
#pragma unroll
        for (int i = 0; i < 4; i++) {
            floatx4 v = {0.f, 0.f, 0.f, 0.f};
            if (valid) v = ((const floatx4*)srcx)[i];
            half4h h = {(_Float16)v[0], (_Float16)v[1], (_Float16)v[2], (_Float16)v[3]};
            *(half4h*)(dstx + i * 4) = h;
        }
        const float* srca = agg + gm * 128 + seg * 32;
        _Float16* dsta = &sIn[m][64 + seg * 32];
#pragma unroll
        for (int i = 0; i < 8; i++) {
            floatx4 v = {0.f, 0.f, 0.f, 0.f};
            if (valid) v = ((const floatx4*)srca)[i];
            half4h h = {(_Float16)v[0], (_Float16)v[1], (_Float16)v[2], (_Float16)v[3]};
            *(half4h*)(dsta + i * 4) = h;
        }
    }
    __syncthreads();

    const int lm = lane & 15, q = lane >> 4, koff = q * 8;
    half8 a[6];
#pragma unroll
    for (int kb = 0; kb < 6; kb++)
        a[kb] = *(const half8*)&sIn[wv * 16 + lm][kb * 32 + koff];
#pragma unroll
    for (int nt = 0; nt < 8; nt++) {
        floatx4 acc = {0.f, 0.f, 0.f, 0.f};
        const int c = nt * 16 + lm;
#pragma unroll
        for (int kb = 0; kb < 6; kb++) {
            half8 b = *(const half8*)&sW[c][kb * 32 + koff];
            acc = MFMA16(a[kb], b, acc);
        }
        float s  = acc[0] + acc[1] + acc[2] + acc[3];
        float ss = acc[0]*acc[0] + acc[1]*acc[1] + acc[2]*acc[2] + acc[3]*acc[3];
        s = col_reduce16(s); ss = col_reduce16(ss);
        if (q == 0) { atomicAdd(&sSum[c], s); atomicAdd(&sSq[c], ss); }
#pragma unroll
        for (int r = 0; r < 4; r++) {
            int m2 = wv * 16 + q * 4 + r;
            long gm2 = e0 + m2;
            if (gm2 < N) h3[gm2 * 128 + c] = acc[r];
        }
    }
    __syncthreads();
    if (tid < 128) {
        int slot = blockIdx.x & 15;
        unsafeAtomicAdd(&gsum[slot * 128 + tid], sSum[tid]);
        unsafeAtomicAdd(&gsq[slot * 128 + tid], sSq[tid]);
    }
}

// -------------------------------------------------------------- k_node_b ----
__global__ __launch_bounds__(512, 2) void k_node_b(
    const float* __restrict__ h3, const _Float16* __restrict__ w2bt,
    const float* __restrict__ scale, const float* __restrict__ shift,
    const float* __restrict__ b2b, float* __restrict__ out, int N) {
    __shared__ _Float16 sH[128][136];
    __shared__ _Float16 sW[64][136];
    const int tid = threadIdx.x, lane = tid & 63, wv = tid >> 6;
    const long e0 = (long)blockIdx.x * 128;

    {
        int n = tid >> 3, seg = (tid & 7) * 16;
        const half8* src = (const half8*)(w2bt + n * 128 + seg);
        half8* dst = (half8*)&sW[n][seg];
        dst[0] = src[0]; dst[1] = src[1];
    }
    {
        int m = tid >> 2, seg = (tid & 3) * 32;
        long gm = e0 + m;
        bool valid = gm < N;
        const float* src = h3 + gm * 128 + seg;
        _Float16* dst = &sH[m][seg];
#pragma unroll
        for (int i = 0; i < 8; i++) {
            floatx4 v = {0.f, 0.f, 0.f, 0.f};
            if (valid) v = ((const floatx4*)src)[i];
            floatx4 sc = ((const floatx4*)(scale + seg))[i];
            floatx4 sh = ((const floatx4*)(shift + seg))[i];
            half4h h;
#pragma unroll
            for (int j = 0; j < 4; j++)
                h[j] = (_Float16)fmaxf(v[j] * sc[j] + sh[j], 0.f);
            *(half4h*)(dst + i * 4) = h;
        }
    }
    __syncthreads();

    const int lm = lane & 15, q = lane >> 4, koff = q * 8;
    half8 a[4];
#pragma unroll
    for (int kb = 0; kb < 4; kb++)
        a[kb] = *(const half8*)&sH[wv * 16 + lm][kb * 32 + koff];
#pragma unroll
    for (int nt = 0; nt < 4; nt++) {
        floatx4 acc = {0.f, 0.f, 0.f, 0.f};
        const int c = nt * 16 + lm;
#pragma unroll
        for (int kb = 0; kb < 4; kb++) {
            half8 b = *(const half8*)&sW[c][kb * 32 + koff];
            acc = MFMA16(a[kb], b, acc);
        }
        float bb = b2b[c];
#pragma unroll
        for (int r = 0; r < 4; r++) {
            int m2 = wv * 16 + q * 4 + r;
            long gm2 = e0 + m2;
            if (gm2 < N) out[gm2 * 64 + c] = acc[r] + bb;
        }
    }
}

// --------------------------------------------------------------- launch -----
extern "C" void kernel_launch(void* const* d_in, const int* in_sizes, int n_in,
                              void* d_out, int out_size, void* d_ws, size_t ws_size,
                              hipStream_t stream) {
    const float* x    = (const float*)d_in[0];
    const int*   eidx = (const int*)d_in[1];
    const float* ea   = (const float*)d_in[2];
    const float* W1a  = (const float*)d_in[5];
    const float* g1a  = (const float*)d_in[7];
    const float* be1a = (const float*)d_in[8];
    const float* W2a  = (const float*)d_in[9];
    const float* b2a  = (const float*)d_in[10];
    const float* W1b  = (const float*)d_in[11];
    const float* g1b  = (const float*)d_in[13];
    const float* be1b = (const float*)d_in[14];
    const float* W2b  = (const float*)d_in[15];
    const float* b2b  = (const float*)d_in[16];
    const int N = in_sizes[0] / 64;
    const int E = in_sizes[2] / 64;
    const int* rowi = eidx;
    const int* coli = eidx + E;

    // workspace layout (float-sized slots, all 16B-aligned chunks)
    float* ws    = (float*)d_ws;
    float* agg   = ws;                          // N*128 f32
    float* h3    = agg + (size_t)N * 128;       // N*128 f32
    float* st    = h3 + (size_t)N * 128;        // 9216
    float* sumE  = st,        * sqE = st + 2048;
    float* sumN  = st + 4096, * sqN = st + 6144;
    float* scE   = st + 8192, * shE = st + 8320;
    float* scN   = st + 8448, * shN = st + 8576;
    int*   cnt    = (int*)(st + 9216);          // N
    int*   cursor = cnt + 50176;                // N
    int*   perm   = cursor + 50176;             // E
    int*   srow   = perm + 800000;              // E
    int*   sdst   = srow + 800000;              // E
    _Float16* x16 = (_Float16*)(sdst + 800000); // N*64 halves
    _Float16* wh  = x16 + (size_t)N * 64 + ((size_t)N * 64 & 4 ? 4 : 0);
    _Float16* w1at = wh;
    _Float16* w2at = wh + 16384;
    _Float16* w1bt = wh + 32768;
    _Float16* w2bt = wh + 57344;

    hipMemsetAsync(agg, 0, (size_t)N * 128 * sizeof(float), stream);
    hipMemsetAsync(st, 0, 8192 * sizeof(float), stream);
    hipMemsetAsync(cnt, 0, (size_t)N * sizeof(int), stream);

    k_prep<<<256, 256, 0, stream>>>(W1a, W2a, W1b, W2b, w1at, w2at, w1bt, w2bt);
    int n4 = N * 16;   // N*64/4
    k_cvt_x<<<(n4 + 511) / 512, 512, 0, stream>>>(x, x16, n4);
    k_hist<<<(E + 255) / 256, 256, 0, stream>>>(coli, cnt, E);
    k_scan<<<1, 1024, 0, stream>>>(cnt, cursor, N);
    k_perm<<<(E + 255) / 256, 256, 0, stream>>>(coli, rowi, cursor, perm, srow, sdst, E);

    int nCh = E / 16;                           // 50000
    k_edge_stats<<<1024, 512, 0, stream>>>(x16, rowi, ea, w1at, sumE, sqE, nCh);
    k_finalize<<<1, 128, 0, stream>>>(sumE, sqE, g1a, be1a, scE, shE, (float)E);
    k_edge_mlp<<<256, 1024, 0, stream>>>(x16, ea, perm, srow, sdst, w1at, w2at,
                                         scE, shE, b2a, agg, nCh);
    int nbl = (N + 127) / 128;
    k_node_a<<<nbl, 512, 0, stream>>>(x, agg, w1bt, h3, sumN, sqN, N);
    k_finalize<<<1, 128, 0, stream>>>(sumN, sqN, g1b, be1b, scN, shN, (float)N);
    k_node_b<<<nbl, 512, 0, stream>>>(h3, w2bt, scN, shN, b2b, (float*)d_out, N);
}